// Round 1
// baseline (351.431 us; speedup 1.0000x reference)
//
#include <hip/hip_runtime.h>
#include <hip/hip_bf16.h>

#define SEQ 2048
#define EMB 1024
#define NH 8
#define HD 64
#define DVH 128
#define LAMBDA_INIT 0.7836057665316245f
#define ONE_MINUS_LI 0.2163942334683755f
#define RMS_EPS 1e-5f

typedef __attribute__((ext_vector_type(8))) short short8_t;
typedef __attribute__((ext_vector_type(4))) float f32x4;

__device__ __forceinline__ short f2bf(float f) {
    __hip_bfloat16 h = __float2bfloat16(f);
    return *reinterpret_cast<short*>(&h);
}
__device__ __forceinline__ float bf2f(short s) {
    unsigned u = ((unsigned)(unsigned short)s) << 16;
    return __uint_as_float(u);
}

// ---------- prep: x f32 -> bf16 ----------
__global__ void k_convert_x(const float* __restrict__ x, short* __restrict__ xb) {
    int i = blockIdx.x * blockDim.x + threadIdx.x;  // one float4 per thread
    const float4* xv = (const float4*)x;
    float4 v = xv[i];
    short4 r = make_short4(f2bf(v.x), f2bf(v.y), f2bf(v.z), f2bf(v.w));
    *(short4*)(xb + i * 4) = r;
}

// ---------- prep: weights f32 (K,N) -> bf16 transposed (N,K) ----------
__global__ void k_transpose_w(const float* __restrict__ w0, const float* __restrict__ w1,
                              const float* __restrict__ w2, const float* __restrict__ w3,
                              short* __restrict__ o0, short* __restrict__ o1,
                              short* __restrict__ o2, short* __restrict__ o3) {
    const float* w = blockIdx.z == 0 ? w0 : blockIdx.z == 1 ? w1 : blockIdx.z == 2 ? w2 : w3;
    short* o = blockIdx.z == 0 ? o0 : blockIdx.z == 1 ? o1 : blockIdx.z == 2 ? o2 : o3;
    __shared__ float t[64][65];
    int r0 = blockIdx.y * 64, c0 = blockIdx.x * 64;
    int tid = threadIdx.x, col = tid & 63, rb = tid >> 6;
#pragma unroll
    for (int i = 0; i < 16; i++) {
        int row = rb + i * 4;
        t[row][col] = w[(r0 + row) * EMB + c0 + col];
    }
    __syncthreads();
#pragma unroll
    for (int i = 0; i < 16; i++) {
        int fr = rb + i * 4;
        o[(c0 + fr) * EMB + r0 + col] = f2bf(t[col][fr]);
    }
}

// ---------- prep: lambda scalar ----------
__global__ void k_lambda(const float* __restrict__ lq1, const float* __restrict__ lk1,
                         const float* __restrict__ lq2, const float* __restrict__ lk2,
                         float* __restrict__ lam) {
    int l = threadIdx.x;
    float p1 = lq1[l] * lk1[l], p2 = lq2[l] * lk2[l];
#pragma unroll
    for (int off = 32; off >= 1; off >>= 1) {
        p1 += __shfl_xor(p1, off);
        p2 += __shfl_xor(p2, off);
    }
    if (l == 0) lam[0] = expf(p1) - expf(p2) + LAMBDA_INIT;
}

// ---------- QKV GEMM: C = A(M,K) * Bt(N,K)^T, bf16 in, bf16 out ----------
__global__ __launch_bounds__(256) void k_gemm_qkv(const short* __restrict__ A,
                                                  const short* __restrict__ wqt,
                                                  const short* __restrict__ wkt,
                                                  const short* __restrict__ wvt,
                                                  short* __restrict__ Qb, short* __restrict__ Kb,
                                                  short* __restrict__ Vb) {
    const int bn = blockIdx.x * 64;
    const int bm = blockIdx.y * 64;
    const int nsel = bn >> 10;
    const int nloc = bn & 1023;
    const short* Bt = nsel == 0 ? wqt : (nsel == 1 ? wkt : wvt);
    short* C = nsel == 0 ? Qb : (nsel == 1 ? Kb : Vb);
    const int tid = threadIdx.x;
    const int w = tid >> 6, l = tid & 63;
    const int lr = l & 15, lg = l >> 4;
    const int mw = bm + (w >> 1) * 32;
    const int nw = nloc + (w & 1) * 32;
    f32x4 zero4 = {0.f, 0.f, 0.f, 0.f};
    f32x4 acc[2][2];
#pragma unroll
    for (int mi = 0; mi < 2; mi++)
#pragma unroll
        for (int ni = 0; ni < 2; ni++) acc[mi][ni] = zero4;
    for (int k0 = 0; k0 < EMB; k0 += 32) {
        short8_t a[2], b[2];
#pragma unroll
        for (int mi = 0; mi < 2; mi++)
            a[mi] = *(const short8_t*)(A + (mw + mi * 16 + lr) * EMB + k0 + lg * 8);
#pragma unroll
        for (int ni = 0; ni < 2; ni++)
            b[ni] = *(const short8_t*)(Bt + (nw + ni * 16 + lr) * EMB + k0 + lg * 8);
#pragma unroll
        for (int mi = 0; mi < 2; mi++)
#pragma unroll
            for (int ni = 0; ni < 2; ni++)
                acc[mi][ni] = __builtin_amdgcn_mfma_f32_16x16x32_bf16(a[mi], b[ni], acc[mi][ni], 0, 0, 0);
    }
#pragma unroll
    for (int mi = 0; mi < 2; mi++)
#pragma unroll
        for (int ni = 0; ni < 2; ni++)
#pragma unroll
            for (int r = 0; r < 4; r++) {
                int row = mw + mi * 16 + lg * 4 + r;
                int col = nw + ni * 16 + lr;
                C[row * EMB + col] = f2bf(acc[mi][ni][r]);
            }
}

// ---------- RoPE on Q,K in place (interleaved pairs as u32) ----------
__global__ void k_rope(short* __restrict__ Qb, short* __restrict__ Kb,
                       const float* __restrict__ cosT, const float* __restrict__ sinT) {
    int i = blockIdx.x * blockDim.x + threadIdx.x;  // pair index == u32 index
    int s = i >> 9;
    int j = i & 31;
    float c = cosT[s * 32 + j], sn = sinT[s * 32 + j];
    unsigned* qw = reinterpret_cast<unsigned*>(Qb);
    unsigned* kw = reinterpret_cast<unsigned*>(Kb);
    unsigned v = qw[i];
    float e = bf2f((short)(v & 0xffff)), o = bf2f((short)(v >> 16));
    float r1 = e * c - o * sn, r2 = e * sn + o * c;
    qw[i] = ((unsigned)(unsigned short)f2bf(r2) << 16) | (unsigned)(unsigned short)f2bf(r1);
    v = kw[i];
    e = bf2f((short)(v & 0xffff));
    o = bf2f((short)(v >> 16));
    r1 = e * c - o * sn;
    r2 = e * sn + o * c;
    kw[i] = ((unsigned)(unsigned short)f2bf(r2) << 16) | (unsigned)(unsigned short)f2bf(r1);
}

// ---------- V transpose: (S, EMB) -> (EMB, S) ----------
__global__ void k_transpose_v(const short* __restrict__ Vb, short* __restrict__ Vt) {
    __shared__ short t[64][65];
    int s0 = blockIdx.x * 64, f0 = blockIdx.y * 64;
    int tid = threadIdx.x, col = tid & 63, rb = tid >> 6;
#pragma unroll
    for (int i = 0; i < 16; i++) {
        int row = rb + i * 4;
        t[row][col] = Vb[(s0 + row) * EMB + f0 + col];
    }
    __syncthreads();
#pragma unroll
    for (int i = 0; i < 16; i++) {
        int fr = rb + i * 4;
        Vt[(f0 + fr) * SEQ + s0 + col] = t[col][fr];
    }
}

// ---------- fused differential flash attention + RMS + subln ----------
__global__ __launch_bounds__(64) void k_attn(const short* __restrict__ Qb,
                                             const short* __restrict__ Kb,
                                             const short* __restrict__ Vt,
                                             const float* __restrict__ lamp,
                                             const float* __restrict__ subln,
                                             short* __restrict__ Ab) {
    const int h = blockIdx.y;
    const int q0 = blockIdx.x * 16;
    const int l = threadIdx.x;
    const int lr = l & 15, lg = l >> 4;
    const float lam = lamp[0];
    __shared__ short pl[16][32];

    short8_t aq1[2], aq2[2];
    {
        const short* qp = Qb + (q0 + lr) * EMB + h * DVH;
        aq1[0] = *(const short8_t*)(qp + lg * 8);
        aq1[1] = *(const short8_t*)(qp + 32 + lg * 8);
        aq2[0] = *(const short8_t*)(qp + 64 + lg * 8);
        aq2[1] = *(const short8_t*)(qp + 96 + lg * 8);
    }
    f32x4 zero4 = {0.f, 0.f, 0.f, 0.f};
    f32x4 o1[8], o2[8];
#pragma unroll
    for (int nt = 0; nt < 8; nt++) {
        o1[nt] = zero4;
        o2[nt] = zero4;
    }
    float m1[4], m2[4], l1[4], l2[4];
#pragma unroll
    for (int r = 0; r < 4; r++) {
        m1[r] = -1e30f;
        m2[r] = -1e30f;
        l1[r] = 0.f;
        l2[r] = 0.f;
    }

    const int nkv = (q0 + 16 + 31) / 32;
    for (int kb = 0; kb < nkv; kb++) {
        const int k0 = kb * 32;
        short8_t vb[8];
#pragma unroll
        for (int nt = 0; nt < 8; nt++)
            vb[nt] = *(const short8_t*)(Vt + (h * DVH + nt * 16 + lr) * SEQ + k0 + lg * 8);
        const short* kpa = Kb + (k0 + lr) * EMB + h * DVH;
        const short* kpb = Kb + (k0 + 16 + lr) * EMB + h * DVH;
        // ---- lambda component 1 ----
        {
            f32x4 sa = zero4, sb = zero4;
            short8_t bk;
            bk = *(const short8_t*)(kpa + lg * 8);
            sa = __builtin_amdgcn_mfma_f32_16x16x32_bf16(aq1[0], bk, sa, 0, 0, 0);
            bk = *(const short8_t*)(kpa + 32 + lg * 8);
            sa = __builtin_amdgcn_mfma_f32_16x16x32_bf16(aq1[1], bk, sa, 0, 0, 0);
            bk = *(const short8_t*)(kpb + lg * 8);
            sb = __builtin_amdgcn_mfma_f32_16x16x32_bf16(aq1[0], bk, sb, 0, 0, 0);
            bk = *(const short8_t*)(kpb + 32 + lg * 8);
            sb = __builtin_amdgcn_mfma_f32_16x16x32_bf16(aq1[1], bk, sb, 0, 0, 0);
            float alpha[4];
#pragma unroll
            for (int r = 0; r < 4; r++) {
                int qr = q0 + lg * 4 + r;
                float va = (k0 + lr <= qr) ? sa[r] * 0.125f : -1e30f;
                float vbs = (k0 + 16 + lr <= qr) ? sb[r] * 0.125f : -1e30f;
                float tm = fmaxf(va, vbs);
#pragma unroll
                for (int off = 1; off < 16; off <<= 1) tm = fmaxf(tm, __shfl_xor(tm, off));
                float mn = fmaxf(m1[r], tm);
                alpha[r] = expf(m1[r] - mn);
                float pa = expf(va - mn), pb = expf(vbs - mn);
                l1[r] = l1[r] * alpha[r] + pa + pb;
                m1[r] = mn;
                pl[lg * 4 + r][lr] = f2bf(pa);
                pl[lg * 4 + r][16 + lr] = f2bf(pb);
            }
#pragma unroll
            for (int nt = 0; nt < 8; nt++)
#pragma unroll
                for (int r = 0; r < 4; r++) o1[nt][r] *= alpha[r];
            __syncthreads();
            short8_t pA = *(const short8_t*)(&pl[lr][lg * 8]);
#pragma unroll
            for (int nt = 0; nt < 8; nt++)
                o1[nt] = __builtin_amdgcn_mfma_f32_16x16x32_bf16(pA, vb[nt], o1[nt], 0, 0, 0);
            __syncthreads();
        }
        // ---- lambda component 2 ----
        {
            f32x4 sa = zero4, sb = zero4;
            short8_t bk;
            bk = *(const short8_t*)(kpa + 64 + lg * 8);
            sa = __builtin_amdgcn_mfma_f32_16x16x32_bf16(aq2[0], bk, sa, 0, 0, 0);
            bk = *(const short8_t*)(kpa + 96 + lg * 8);
            sa = __builtin_amdgcn_mfma_f32_16x16x32_bf16(aq2[1], bk, sa, 0, 0, 0);
            bk = *(const short8_t*)(kpb + 64 + lg * 8);
            sb = __builtin_amdgcn_mfma_f32_16x16x32_bf16(aq2[0], bk, sb, 0, 0, 0);
            bk = *(const short8_t*)(kpb + 96 + lg * 8);
            sb = __builtin_amdgcn_mfma_f32_16x16x32_bf16(aq2[1], bk, sb, 0, 0, 0);
            float alpha[4];
#pragma unroll
            for (int r = 0; r < 4; r++) {
                int qr = q0 + lg * 4 + r;
                float va = (k0 + lr <= qr) ? sa[r] * 0.125f : -1e30f;
                float vbs = (k0 + 16 + lr <= qr) ? sb[r] * 0.125f : -1e30f;
                float tm = fmaxf(va, vbs);
#pragma unroll
                for (int off = 1; off < 16; off <<= 1) tm = fmaxf(tm, __shfl_xor(tm, off));
                float mn = fmaxf(m2[r], tm);
                alpha[r] = expf(m2[r] - mn);
                float pa = expf(va - mn), pb = expf(vbs - mn);
                l2[r] = l2[r] * alpha[r] + pa + pb;
                m2[r] = mn;
                pl[lg * 4 + r][lr] = f2bf(pa);
                pl[lg * 4 + r][16 + lr] = f2bf(pb);
            }
#pragma unroll
            for (int nt = 0; nt < 8; nt++)
#pragma unroll
                for (int r = 0; r < 4; r++) o2[nt][r] *= alpha[r];
            __syncthreads();
            short8_t pA = *(const short8_t*)(&pl[lr][lg * 8]);
#pragma unroll
            for (int nt = 0; nt < 8; nt++)
                o2[nt] = __builtin_amdgcn_mfma_f32_16x16x32_bf16(pA, vb[nt], o2[nt], 0, 0, 0);
            __syncthreads();
        }
    }
    // ---- epilogue: 1/l, combine, RMS, subln, (1-lambda_init) ----
    float ls1[4], ls2[4], ssc[4];
#pragma unroll
    for (int r = 0; r < 4; r++) {
        float a = l1[r], b = l2[r];
#pragma unroll
        for (int off = 1; off < 16; off <<= 1) {
            a += __shfl_xor(a, off);
            b += __shfl_xor(b, off);
        }
        ls1[r] = a;
        ls2[r] = b;
    }
    f32x4 co[8];
#pragma unroll
    for (int nt = 0; nt < 8; nt++)
#pragma unroll
        for (int r = 0; r < 4; r++)
            co[nt][r] = o1[nt][r] / ls1[r] - lam * (o2[nt][r] / ls2[r]);
#pragma unroll
    for (int r = 0; r < 4; r++) {
        float s = 0.f;
#pragma unroll
        for (int nt = 0; nt < 8; nt++) s += co[nt][r] * co[nt][r];
#pragma unroll
        for (int off = 1; off < 16; off <<= 1) s += __shfl_xor(s, off);
        ssc[r] = rsqrtf(s * (1.0f / 128.0f) + RMS_EPS) * ONE_MINUS_LI;
    }
#pragma unroll
    for (int nt = 0; nt < 8; nt++) {
        float sw = subln[nt * 16 + lr];
        int col = h * DVH + nt * 16 + lr;
#pragma unroll
        for (int r = 0; r < 4; r++) {
            int row = q0 + lg * 4 + r;
            Ab[row * EMB + col] = f2bf(co[nt][r] * ssc[r] * sw);
        }
    }
}

// ---------- output GEMM: out = Ab(M,K) * wot(N,K)^T, f32 out ----------
__global__ __launch_bounds__(256) void k_gemm_out(const short* __restrict__ A,
                                                  const short* __restrict__ Bt,
                                                  float* __restrict__ C) {
    const int bn = blockIdx.x * 64;
    const int bm = blockIdx.y * 64;
    const int tid = threadIdx.x;
    const int w = tid >> 6, l = tid & 63;
    const int lr = l & 15, lg = l >> 4;
    const int mw = bm + (w >> 1) * 32;
    const int nw = bn + (w & 1) * 32;
    f32x4 zero4 = {0.f, 0.f, 0.f, 0.f};
    f32x4 acc[2][2];
#pragma unroll
    for (int mi = 0; mi < 2; mi++)
#pragma unroll
        for (int ni = 0; ni < 2; ni++) acc[mi][ni] = zero4;
    for (int k0 = 0; k0 < EMB; k0 += 32) {
        short8_t a[2], b[2];
#pragma unroll
        for (int mi = 0; mi < 2; mi++)
            a[mi] = *(const short8_t*)(A + (mw + mi * 16 + lr) * EMB + k0 + lg * 8);
#pragma unroll
        for (int ni = 0; ni < 2; ni++)
            b[ni] = *(const short8_t*)(Bt + (nw + ni * 16 + lr) * EMB + k0 + lg * 8);
#pragma unroll
        for (int mi = 0; mi < 2; mi++)
#pragma unroll
            for (int ni = 0; ni < 2; ni++)
                acc[mi][ni] = __builtin_amdgcn_mfma_f32_16x16x32_bf16(a[mi], b[ni], acc[mi][ni], 0, 0, 0);
    }
#pragma unroll
    for (int mi = 0; mi < 2; mi++)
#pragma unroll
        for (int ni = 0; ni < 2; ni++)
#pragma unroll
            for (int r = 0; r < 4; r++) {
                int row = mw + mi * 16 + lg * 4 + r;
                int col = nw + ni * 16 + lr;
                C[row * EMB + col] = acc[mi][ni][r];
            }
}

extern "C" void kernel_launch(void* const* d_in, const int* in_sizes, int n_in,
                              void* d_out, int out_size, void* d_ws, size_t ws_size,
                              hipStream_t stream) {
    const float* x = (const float*)d_in[0];
    const float* cosT = (const float*)d_in[1];
    const float* sinT = (const float*)d_in[2];
    const float* wq = (const float*)d_in[3];
    const float* wk = (const float*)d_in[4];
    const float* wv = (const float*)d_in[5];
    const float* wo = (const float*)d_in[6];
    const float* lq1 = (const float*)d_in[7];
    const float* lk1 = (const float*)d_in[8];
    const float* lq2 = (const float*)d_in[9];
    const float* lk2 = (const float*)d_in[10];
    const float* subln = (const float*)d_in[11];
    float* out = (float*)d_out;
    char* ws = (char*)d_ws;
    const size_t MB = 1 << 20;
    short* xb = (short*)(ws);
    short* wqt = (short*)(ws + 4 * MB);
    short* wkt = (short*)(ws + 6 * MB);
    short* wvt = (short*)(ws + 8 * MB);
    short* wot = (short*)(ws + 10 * MB);
    short* Qb = (short*)(ws + 12 * MB);
    short* Kb = (short*)(ws + 16 * MB);
    short* Vb = (short*)(ws + 20 * MB);
    short* Vt = (short*)(ws + 24 * MB);
    short* Ab = (short*)(ws + 28 * MB);
    float* lam = (float*)(ws + 32 * MB);

    k_convert_x<<<2048, 256, 0, stream>>>(x, xb);
    k_transpose_w<<<dim3(16, 16, 4), 256, 0, stream>>>(wq, wk, wv, wo, wqt, wkt, wvt, wot);
    k_lambda<<<1, 64, 0, stream>>>(lq1, lk1, lq2, lk2, lam);
    k_gemm_qkv<<<dim3(48, 32), 256, 0, stream>>>(xb, wqt, wkt, wvt, Qb, Kb, Vb);
    k_rope<<<4096, 256, 0, stream>>>(Qb, Kb, cosT, sinT);
    k_transpose_v<<<dim3(32, 16), 256, 0, stream>>>(Vb, Vt);
    k_attn<<<dim3(128, 8), 64, 0, stream>>>(Qb, Kb, Vt, lam, subln, Ab);
    k_gemm_out<<<dim3(16, 32), 256, 0, stream>>>(Ab, wot, out);
}

// Round 2
// 241.549 us; speedup vs baseline: 1.4549x; 1.4549x over previous
//
#include <hip/hip_runtime.h>
#include <hip/hip_bf16.h>

#define SEQ 2048
#define EMB 1024
#define NH 8
#define HD 64
#define DVH 128
#define LAMBDA_INIT 0.7836057665316245f
#define ONE_MINUS_LI 0.2163942334683755f
#define RMS_EPS 1e-5f

typedef __attribute__((ext_vector_type(8))) short short8_t;
typedef __attribute__((ext_vector_type(4))) float f32x4;

__device__ __forceinline__ short f2bf(float f) {
    __hip_bfloat16 h = __float2bfloat16(f);
    return *reinterpret_cast<short*>(&h);
}
__device__ __forceinline__ float bf2f(short s) {
    unsigned u = ((unsigned)(unsigned short)s) << 16;
    return __uint_as_float(u);
}

// ---------- prep: x f32 -> bf16 ----------
__global__ void k_convert_x(const float* __restrict__ x, short* __restrict__ xb) {
    int i = blockIdx.x * blockDim.x + threadIdx.x;  // one float4 per thread
    const float4* xv = (const float4*)x;
    float4 v = xv[i];
    short4 r = make_short4(f2bf(v.x), f2bf(v.y), f2bf(v.z), f2bf(v.w));
    *(short4*)(xb + i * 4) = r;
}

// ---------- prep: weights f32 (K,N) -> bf16 transposed (N,K) ----------
__global__ void k_transpose_w(const float* __restrict__ w0, const float* __restrict__ w1,
                              const float* __restrict__ w2, const float* __restrict__ w3,
                              short* __restrict__ o0, short* __restrict__ o1,
                              short* __restrict__ o2, short* __restrict__ o3) {
    const float* w = blockIdx.z == 0 ? w0 : blockIdx.z == 1 ? w1 : blockIdx.z == 2 ? w2 : w3;
    short* o = blockIdx.z == 0 ? o0 : blockIdx.z == 1 ? o1 : blockIdx.z == 2 ? o2 : o3;
    __shared__ float t[64][65];
    int r0 = blockIdx.y * 64, c0 = blockIdx.x * 64;
    int tid = threadIdx.x, col = tid & 63, rb = tid >> 6;
#pragma unroll
    for (int i = 0; i < 16; i++) {
        int row = rb + i * 4;
        t[row][col] = w[(r0 + row) * EMB + c0 + col];
    }
    __syncthreads();
#pragma unroll
    for (int i = 0; i < 16; i++) {
        int fr = rb + i * 4;
        o[(c0 + fr) * EMB + r0 + col] = f2bf(t[col][fr]);
    }
}

// ---------- prep: lambda scalar ----------
__global__ void k_lambda(const float* __restrict__ lq1, const float* __restrict__ lk1,
                         const float* __restrict__ lq2, const float* __restrict__ lk2,
                         float* __restrict__ lam) {
    int l = threadIdx.x;
    float p1 = lq1[l] * lk1[l], p2 = lq2[l] * lk2[l];
#pragma unroll
    for (int off = 32; off >= 1; off >>= 1) {
        p1 += __shfl_xor(p1, off);
        p2 += __shfl_xor(p2, off);
    }
    if (l == 0) lam[0] = expf(p1) - expf(p2) + LAMBDA_INIT;
}

// ---------- QKV GEMM: C = A(M,K) * Bt(N,K)^T, bf16 in, bf16 out ----------
__global__ __launch_bounds__(256) void k_gemm_qkv(const short* __restrict__ A,
                                                  const short* __restrict__ wqt,
                                                  const short* __restrict__ wkt,
                                                  const short* __restrict__ wvt,
                                                  short* __restrict__ Qb, short* __restrict__ Kb,
                                                  short* __restrict__ Vb) {
    const int bn = blockIdx.x * 64;
    const int bm = blockIdx.y * 64;
    const int nsel = bn >> 10;
    const int nloc = bn & 1023;
    const short* Bt = nsel == 0 ? wqt : (nsel == 1 ? wkt : wvt);
    short* C = nsel == 0 ? Qb : (nsel == 1 ? Kb : Vb);
    const int tid = threadIdx.x;
    const int w = tid >> 6, l = tid & 63;
    const int lr = l & 15, lg = l >> 4;
    const int mw = bm + (w >> 1) * 32;
    const int nw = nloc + (w & 1) * 32;
    f32x4 zero4 = {0.f, 0.f, 0.f, 0.f};
    f32x4 acc[2][2];
#pragma unroll
    for (int mi = 0; mi < 2; mi++)
#pragma unroll
        for (int ni = 0; ni < 2; ni++) acc[mi][ni] = zero4;
    for (int k0 = 0; k0 < EMB; k0 += 32) {
        short8_t a[2], b[2];
#pragma unroll
        for (int mi = 0; mi < 2; mi++)
            a[mi] = *(const short8_t*)(A + (mw + mi * 16 + lr) * EMB + k0 + lg * 8);
#pragma unroll
        for (int ni = 0; ni < 2; ni++)
            b[ni] = *(const short8_t*)(Bt + (nw + ni * 16 + lr) * EMB + k0 + lg * 8);
#pragma unroll
        for (int mi = 0; mi < 2; mi++)
#pragma unroll
            for (int ni = 0; ni < 2; ni++)
                acc[mi][ni] = __builtin_amdgcn_mfma_f32_16x16x32_bf16(a[mi], b[ni], acc[mi][ni], 0, 0, 0);
    }
#pragma unroll
    for (int mi = 0; mi < 2; mi++)
#pragma unroll
        for (int ni = 0; ni < 2; ni++)
#pragma unroll
            for (int r = 0; r < 4; r++) {
                int row = mw + mi * 16 + lg * 4 + r;
                int col = nw + ni * 16 + lr;
                C[row * EMB + col] = f2bf(acc[mi][ni][r]);
            }
}

// ---------- RoPE on Q,K in place (interleaved pairs as u32) ----------
__global__ void k_rope(short* __restrict__ Qb, short* __restrict__ Kb,
                       const float* __restrict__ cosT, const float* __restrict__ sinT) {
    int i = blockIdx.x * blockDim.x + threadIdx.x;  // pair index == u32 index
    int s = i >> 9;
    int j = i & 31;
    float c = cosT[s * 32 + j], sn = sinT[s * 32 + j];
    unsigned* qw = reinterpret_cast<unsigned*>(Qb);
    unsigned* kw = reinterpret_cast<unsigned*>(Kb);
    unsigned v = qw[i];
    float e = bf2f((short)(v & 0xffff)), o = bf2f((short)(v >> 16));
    float r1 = e * c - o * sn, r2 = e * sn + o * c;
    qw[i] = ((unsigned)(unsigned short)f2bf(r2) << 16) | (unsigned)(unsigned short)f2bf(r1);
    v = kw[i];
    e = bf2f((short)(v & 0xffff));
    o = bf2f((short)(v >> 16));
    r1 = e * c - o * sn;
    r2 = e * sn + o * c;
    kw[i] = ((unsigned)(unsigned short)f2bf(r2) << 16) | (unsigned)(unsigned short)f2bf(r1);
}

// ---------- V transpose: (S, EMB) -> (EMB, S) ----------
__global__ void k_transpose_v(const short* __restrict__ Vb, short* __restrict__ Vt) {
    __shared__ short t[64][65];
    int s0 = blockIdx.x * 64, f0 = blockIdx.y * 64;
    int tid = threadIdx.x, col = tid & 63, rb = tid >> 6;
#pragma unroll
    for (int i = 0; i < 16; i++) {
        int row = rb + i * 4;
        t[row][col] = Vb[(s0 + row) * EMB + f0 + col];
    }
    __syncthreads();
#pragma unroll
    for (int i = 0; i < 16; i++) {
        int fr = rb + i * 4;
        Vt[(f0 + fr) * SEQ + s0 + col] = t[col][fr];
    }
}

// ---------- fused differential flash attention + RMS + subln ----------
// 4 waves/block; wave w handles KV blocks w, w+4, ... (strided, balanced);
// swapped QK^T (S^T = mfma(K,Q)) so the causal mask and softmax max are
// nearly lane-local; per-wave-private LDS P-bounce (no barriers in loop);
// deferred O-rescale (THR=8); block-level combine of (m,l,O) partials.
__global__ __launch_bounds__(256) void k_attn(const short* __restrict__ Qb,
                                              const short* __restrict__ Kb,
                                              const short* __restrict__ Vt,
                                              const float* __restrict__ lamp,
                                              const float* __restrict__ subln,
                                              short* __restrict__ Ab) {
    const int h = blockIdx.y;
    const int q0 = (gridDim.x - 1 - blockIdx.x) * 16;  // longest blocks first
    const int tid = threadIdx.x;
    const int w = tid >> 6;
    const int l = tid & 63;
    const int lq = l & 15;  // q-col in S^T / dv-col in O
    const int lg = l >> 4;  // lane group 0..3
    const float lam = lamp[0];

    __shared__ __align__(16) float OC[4][16][132];  // 33 KB combine buffer
    __shared__ float ML[4][4][16];                  // m1,l1,m2,l2 per wave
    __shared__ __align__(16) short PL[4][16][40];   // per-wave P bounce

    const int T = q0 + 16;          // exclusive causal bound
    const int nblk = (T + 31) >> 5; // 32-wide KV blocks

    // Q fragments (B-operand): lane holds Q[q0+lq][32*s + 8*lg + j]
    short8_t qf[4];
    {
        const short* qp = Qb + (q0 + lq) * EMB + h * DVH + lg * 8;
        qf[0] = *(const short8_t*)(qp);
        qf[1] = *(const short8_t*)(qp + 32);
        qf[2] = *(const short8_t*)(qp + 64);
        qf[3] = *(const short8_t*)(qp + 96);
    }
    f32x4 zero4 = {0.f, 0.f, 0.f, 0.f};
    f32x4 o1[8], o2[8];
#pragma unroll
    for (int dt = 0; dt < 8; dt++) {
        o1[dt] = zero4;
        o2[dt] = zero4;
    }
    float m1 = -1e30f, m2 = -1e30f, l1 = 0.f, l2 = 0.f;
    short* myP = &PL[w][0][0];
    unsigned* myP32 = reinterpret_cast<unsigned*>(myP);

    for (int kb = w; kb < nblk; kb += 4) {
        const int k0 = kb * 32;
        const bool edge = (k0 + 31 > q0);
        const short* kp = Kb + (k0 + lq) * EMB + h * DVH + lg * 8;
        // K fragments (A-operand): lane holds K[k0+16t+lq][32*s + 8*lg + j]
        short8_t kf[2][4];
#pragma unroll
        for (int t = 0; t < 2; t++)
#pragma unroll
            for (int s = 0; s < 4; s++)
                kf[t][s] = *(const short8_t*)(kp + t * 16 * EMB + s * 32);
        // V fragments (B-operand, shared by both components)
        short8_t vf[8];
#pragma unroll
        for (int dt = 0; dt < 8; dt++)
            vf[dt] = *(const short8_t*)(Vt + (h * DVH + dt * 16 + lq) * SEQ + k0 + lg * 8);

        f32x4 s1[2], s2[2];
#pragma unroll
        for (int t = 0; t < 2; t++) {
            s1[t] = zero4;
            s2[t] = zero4;
            s1[t] = __builtin_amdgcn_mfma_f32_16x16x32_bf16(kf[t][0], qf[0], s1[t], 0, 0, 0);
            s1[t] = __builtin_amdgcn_mfma_f32_16x16x32_bf16(kf[t][1], qf[1], s1[t], 0, 0, 0);
            s2[t] = __builtin_amdgcn_mfma_f32_16x16x32_bf16(kf[t][2], qf[2], s2[t], 0, 0, 0);
            s2[t] = __builtin_amdgcn_mfma_f32_16x16x32_bf16(kf[t][3], qf[3], s2[t], 0, 0, 0);
        }

        // ---- component 1 softmax + PV ----
        {
            float sv[8];
#pragma unroll
            for (int t = 0; t < 2; t++)
#pragma unroll
                for (int r = 0; r < 4; r++) sv[t * 4 + r] = s1[t][r] * 0.125f;
            if (edge) {
#pragma unroll
                for (int t = 0; t < 2; t++)
#pragma unroll
                    for (int r = 0; r < 4; r++)
                        if (k0 + t * 16 + lg * 4 + r > q0 + lq) sv[t * 4 + r] = -1e30f;
            }
            float t1 = sv[0];
#pragma unroll
            for (int i = 1; i < 8; i++) t1 = fmaxf(t1, sv[i]);
            t1 = fmaxf(t1, __shfl_xor(t1, 16));
            t1 = fmaxf(t1, __shfl_xor(t1, 32));
            if (!__all(t1 <= m1 + 8.f)) {
                float mn = fmaxf(m1, t1);
                float al = __expf(m1 - mn);
                m1 = mn;
                l1 *= al;
                float ar[4];
#pragma unroll
                for (int r = 0; r < 4; r++) ar[r] = __shfl(al, lg * 4 + r);
#pragma unroll
                for (int dt = 0; dt < 8; dt++)
#pragma unroll
                    for (int r = 0; r < 4; r++) o1[dt][r] *= ar[r];
            }
            float p[8];
#pragma unroll
            for (int i = 0; i < 8; i++) {
                p[i] = __expf(sv[i] - m1);
                l1 += p[i];
            }
#pragma unroll
            for (int t = 0; t < 2; t++) {
                unsigned u0 = ((unsigned)(unsigned short)f2bf(p[t * 4 + 1]) << 16) |
                              (unsigned)(unsigned short)f2bf(p[t * 4 + 0]);
                unsigned u1 = ((unsigned)(unsigned short)f2bf(p[t * 4 + 3]) << 16) |
                              (unsigned)(unsigned short)f2bf(p[t * 4 + 2]);
                int base = lq * 20 + t * 8 + lg * 2;
                myP32[base] = u0;
                myP32[base + 1] = u1;
            }
            short8_t pa = *(const short8_t*)(myP + lq * 40 + lg * 8);
#pragma unroll
            for (int dt = 0; dt < 8; dt++)
                o1[dt] = __builtin_amdgcn_mfma_f32_16x16x32_bf16(pa, vf[dt], o1[dt], 0, 0, 0);
        }
        // ---- component 2 softmax + PV ----
        {
            float sv[8];
#pragma unroll
            for (int t = 0; t < 2; t++)
#pragma unroll
                for (int r = 0; r < 4; r++) sv[t * 4 + r] = s2[t][r] * 0.125f;
            if (edge) {
#pragma unroll
                for (int t = 0; t < 2; t++)
#pragma unroll
                    for (int r = 0; r < 4; r++)
                        if (k0 + t * 16 + lg * 4 + r > q0 + lq) sv[t * 4 + r] = -1e30f;
            }
            float t1 = sv[0];
#pragma unroll
            for (int i = 1; i < 8; i++) t1 = fmaxf(t1, sv[i]);
            t1 = fmaxf(t1, __shfl_xor(t1, 16));
            t1 = fmaxf(t1, __shfl_xor(t1, 32));
            if (!__all(t1 <= m2 + 8.f)) {
                float mn = fmaxf(m2, t1);
                float al = __expf(m2 - mn);
                m2 = mn;
                l2 *= al;
                float ar[4];
#pragma unroll
                for (int r = 0; r < 4; r++) ar[r] = __shfl(al, lg * 4 + r);
#pragma unroll
                for (int dt = 0; dt < 8; dt++)
#pragma unroll
                    for (int r = 0; r < 4; r++) o2[dt][r] *= ar[r];
            }
            float p[8];
#pragma unroll
            for (int i = 0; i < 8; i++) {
                p[i] = __expf(sv[i] - m2);
                l2 += p[i];
            }
#pragma unroll
            for (int t = 0; t < 2; t++) {
                unsigned u0 = ((unsigned)(unsigned short)f2bf(p[t * 4 + 1]) << 16) |
                              (unsigned)(unsigned short)f2bf(p[t * 4 + 0]);
                unsigned u1 = ((unsigned)(unsigned short)f2bf(p[t * 4 + 3]) << 16) |
                              (unsigned)(unsigned short)f2bf(p[t * 4 + 2]);
                int base = lq * 20 + t * 8 + lg * 2;
                myP32[base] = u0;
                myP32[base + 1] = u1;
            }
            short8_t pa = *(const short8_t*)(myP + lq * 40 + lg * 8);
#pragma unroll
            for (int dt = 0; dt < 8; dt++)
                o2[dt] = __builtin_amdgcn_mfma_f32_16x16x32_bf16(pa, vf[dt], o2[dt], 0, 0, 0);
        }
    }

    // ---- block-level combine ----
    l1 += __shfl_xor(l1, 16);
    l1 += __shfl_xor(l1, 32);
    l2 += __shfl_xor(l2, 16);
    l2 += __shfl_xor(l2, 32);
    if (l < 16) {
        ML[w][0][l] = m1;
        ML[w][1][l] = l1;
        ML[w][2][l] = m2;
        ML[w][3][l] = l2;
    }
    __syncthreads();
    // weight own O1 partial, dump to OC
    {
        float ww[4];
#pragma unroll
        for (int r = 0; r < 4; r++) {
            int qr = lg * 4 + r;
            float mx = fmaxf(fmaxf(ML[0][0][qr], ML[1][0][qr]), fmaxf(ML[2][0][qr], ML[3][0][qr]));
            ww[r] = __expf(ML[w][0][qr] - mx);
        }
#pragma unroll
        for (int dt = 0; dt < 8; dt++)
#pragma unroll
            for (int r = 0; r < 4; r++) OC[w][lg * 4 + r][dt * 16 + lq] = o1[dt][r] * ww[r];
    }
    __syncthreads();
    const int eq = tid >> 4;          // output row 0..15
    const int edv = (tid & 15) * 8;   // dv slice
    float co1[8];
    {
        f32x4 a0 = zero4, a1 = zero4;
#pragma unroll
        for (int ww = 0; ww < 4; ww++) {
            a0 += *(const f32x4*)&OC[ww][eq][edv];
            a1 += *(const f32x4*)&OC[ww][eq][edv + 4];
        }
#pragma unroll
        for (int j = 0; j < 4; j++) {
            co1[j] = a0[j];
            co1[4 + j] = a1[j];
        }
    }
    __syncthreads();
    {
        float ww[4];
#pragma unroll
        for (int r = 0; r < 4; r++) {
            int qr = lg * 4 + r;
            float mx = fmaxf(fmaxf(ML[0][2][qr], ML[1][2][qr]), fmaxf(ML[2][2][qr], ML[3][2][qr]));
            ww[r] = __expf(ML[w][2][qr] - mx);
        }
#pragma unroll
        for (int dt = 0; dt < 8; dt++)
#pragma unroll
            for (int r = 0; r < 4; r++) OC[w][lg * 4 + r][dt * 16 + lq] = o2[dt][r] * ww[r];
    }
    __syncthreads();
    float co2[8];
    {
        f32x4 a0 = zero4, a1 = zero4;
#pragma unroll
        for (int ww = 0; ww < 4; ww++) {
            a0 += *(const f32x4*)&OC[ww][eq][edv];
            a1 += *(const f32x4*)&OC[ww][eq][edv + 4];
        }
#pragma unroll
        for (int j = 0; j < 4; j++) {
            co2[j] = a0[j];
            co2[4 + j] = a1[j];
        }
    }
    // totals
    float M1 = fmaxf(fmaxf(ML[0][0][eq], ML[1][0][eq]), fmaxf(ML[2][0][eq], ML[3][0][eq]));
    float M2 = fmaxf(fmaxf(ML[0][2][eq], ML[1][2][eq]), fmaxf(ML[2][2][eq], ML[3][2][eq]));
    float L1 = 0.f, L2 = 0.f;
#pragma unroll
    for (int ww = 0; ww < 4; ww++) {
        L1 += __expf(ML[ww][0][eq] - M1) * ML[ww][1][eq];
        L2 += __expf(ML[ww][2][eq] - M2) * ML[ww][3][eq];
    }
    float inv1 = 1.f / L1, inv2 = lam / L2;
    float a[8], ss = 0.f;
#pragma unroll
    for (int j = 0; j < 8; j++) {
        a[j] = co1[j] * inv1 - co2[j] * inv2;
        ss += a[j] * a[j];
    }
    ss += __shfl_xor(ss, 1);
    ss += __shfl_xor(ss, 2);
    ss += __shfl_xor(ss, 4);
    ss += __shfl_xor(ss, 8);
    float sc = rsqrtf(ss * (1.0f / 128.0f) + RMS_EPS) * ONE_MINUS_LI;
    short8_t r8;
#pragma unroll
    for (int j = 0; j < 8; j++) r8[j] = f2bf(a[j] * sc * subln[edv + j]);
    *(short8_t*)(Ab + (q0 + eq) * EMB + h * DVH + edv) = r8;
}

// ---------- output GEMM: out = Ab(M,K) * wot(N,K)^T, f32 out ----------
__global__ __launch_bounds__(256) void k_gemm_out(const short* __restrict__ A,
                                                  const short* __restrict__ Bt,
                                                  float* __restrict__ C) {
    const int bn = blockIdx.x * 64;
    const int bm = blockIdx.y * 64;
    const int tid = threadIdx.x;
    const int w = tid >> 6, l = tid & 63;
    const int lr = l & 15, lg = l >> 4;
    const int mw = bm + (w >> 1) * 32;
    const int nw = bn + (w & 1) * 32;
    f32x4 zero4 = {0.f, 0.f, 0.f, 0.f};
    f32x4 acc[2][2];
#pragma unroll
    for (int mi = 0; mi < 2; mi++)
#pragma unroll
        for (int ni = 0; ni < 2; ni++) acc[mi][ni] = zero4;
    for (int k0 = 0; k0 < EMB; k0 += 32) {
        short8_t a[2], b[2];
#pragma unroll
        for (int mi = 0; mi < 2; mi++)
            a[mi] = *(const short8_t*)(A + (mw + mi * 16 + lr) * EMB + k0 + lg * 8);
#pragma unroll
        for (int ni = 0; ni < 2; ni++)
            b[ni] = *(const short8_t*)(Bt + (nw + ni * 16 + lr) * EMB + k0 + lg * 8);
#pragma unroll
        for (int mi = 0; mi < 2; mi++)
#pragma unroll
            for (int ni = 0; ni < 2; ni++)
                acc[mi][ni] = __builtin_amdgcn_mfma_f32_16x16x32_bf16(a[mi], b[ni], acc[mi][ni], 0, 0, 0);
    }
#pragma unroll
    for (int mi = 0; mi < 2; mi++)
#pragma unroll
        for (int ni = 0; ni < 2; ni++)
#pragma unroll
            for (int r = 0; r < 4; r++) {
                int row = mw + mi * 16 + lg * 4 + r;
                int col = nw + ni * 16 + lr;
                C[row * EMB + col] = acc[mi][ni][r];
            }
}

extern "C" void kernel_launch(void* const* d_in, const int* in_sizes, int n_in,
                              void* d_out, int out_size, void* d_ws, size_t ws_size,
                              hipStream_t stream) {
    const float* x = (const float*)d_in[0];
    const float* cosT = (const float*)d_in[1];
    const float* sinT = (const float*)d_in[2];
    const float* wq = (const float*)d_in[3];
    const float* wk = (const float*)d_in[4];
    const float* wv = (const float*)d_in[5];
    const float* wo = (const float*)d_in[6];
    const float* lq1 = (const float*)d_in[7];
    const float* lk1 = (const float*)d_in[8];
    const float* lq2 = (const float*)d_in[9];
    const float* lk2 = (const float*)d_in[10];
    const float* subln = (const float*)d_in[11];
    float* out = (float*)d_out;
    char* ws = (char*)d_ws;
    const size_t MB = 1 << 20;
    short* xb = (short*)(ws);
    short* wqt = (short*)(ws + 4 * MB);
    short* wkt = (short*)(ws + 6 * MB);
    short* wvt = (short*)(ws + 8 * MB);
    short* wot = (short*)(ws + 10 * MB);
    short* Qb = (short*)(ws + 12 * MB);
    short* Kb = (short*)(ws + 16 * MB);
    short* Vb = (short*)(ws + 20 * MB);
    short* Vt = (short*)(ws + 24 * MB);
    short* Ab = (short*)(ws + 28 * MB);
    float* lam = (float*)(ws + 32 * MB);

    k_convert_x<<<2048, 256, 0, stream>>>(x, xb);
    k_transpose_w<<<dim3(16, 16, 4), 256, 0, stream>>>(wq, wk, wv, wo, wqt, wkt, wvt, wot);
    k_lambda<<<1, 64, 0, stream>>>(lq1, lk1, lq2, lk2, lam);
    k_gemm_qkv<<<dim3(48, 32), 256, 0, stream>>>(xb, wqt, wkt, wvt, Qb, Kb, Vb);
    k_rope<<<4096, 256, 0, stream>>>(Qb, Kb, cosT, sinT);
    k_transpose_v<<<dim3(32, 16), 256, 0, stream>>>(Vb, Vt);
    k_attn<<<dim3(128, 8), 256, 0, stream>>>(Qb, Kb, Vt, lam, subln, Ab);
    k_gemm_out<<<dim3(16, 32), 256, 0, stream>>>(Ab, wot, out);
}

// Round 3
// 211.486 us; speedup vs baseline: 1.6617x; 1.1421x over previous
//
#include <hip/hip_runtime.h>
#include <hip/hip_bf16.h>

#define SEQ 2048
#define EMB 1024
#define NH 8
#define HD 64
#define DVH 128
#define LAMBDA_INIT 0.7836057665316245f
#define ONE_MINUS_LI 0.2163942334683755f
#define RMS_EPS 1e-5f

typedef __attribute__((ext_vector_type(8))) short short8_t;
typedef __attribute__((ext_vector_type(4))) float f32x4;

__device__ __forceinline__ short f2bf(float f) {
    __hip_bfloat16 h = __float2bfloat16(f);
    return *reinterpret_cast<short*>(&h);
}
__device__ __forceinline__ float bf2f(short s) {
    unsigned u = ((unsigned)(unsigned short)s) << 16;
    return __uint_as_float(u);
}

// ---------- prep: x f32 -> bf16 ----------
__global__ void k_convert_x(const float* __restrict__ x, short* __restrict__ xb) {
    int i = blockIdx.x * blockDim.x + threadIdx.x;
    const float4* xv = (const float4*)x;
    float4 v = xv[i];
    short4 r = make_short4(f2bf(v.x), f2bf(v.y), f2bf(v.z), f2bf(v.w));
    *(short4*)(xb + i * 4) = r;
}

// ---------- prep: weights f32 (K,N) -> bf16 transposed (N,K) ----------
__global__ void k_transpose_w(const float* __restrict__ w0, const float* __restrict__ w1,
                              const float* __restrict__ w2, const float* __restrict__ w3,
                              short* __restrict__ o0, short* __restrict__ o1,
                              short* __restrict__ o2, short* __restrict__ o3) {
    const float* w = blockIdx.z == 0 ? w0 : blockIdx.z == 1 ? w1 : blockIdx.z == 2 ? w2 : w3;
    short* o = blockIdx.z == 0 ? o0 : blockIdx.z == 1 ? o1 : blockIdx.z == 2 ? o2 : o3;
    __shared__ float t[64][65];
    int r0 = blockIdx.y * 64, c0 = blockIdx.x * 64;
    int tid = threadIdx.x, col = tid & 63, rb = tid >> 6;
#pragma unroll
    for (int i = 0; i < 16; i++) {
        int row = rb + i * 4;
        t[row][col] = w[(r0 + row) * EMB + c0 + col];
    }
    __syncthreads();
#pragma unroll
    for (int i = 0; i < 16; i++) {
        int fr = rb + i * 4;
        o[(c0 + fr) * EMB + r0 + col] = f2bf(t[col][fr]);
    }
}

// ---------- prep: lambda scalar ----------
__global__ void k_lambda(const float* __restrict__ lq1, const float* __restrict__ lk1,
                         const float* __restrict__ lq2, const float* __restrict__ lk2,
                         float* __restrict__ lam) {
    int l = threadIdx.x;
    float p1 = lq1[l] * lk1[l], p2 = lq2[l] * lk2[l];
#pragma unroll
    for (int off = 32; off >= 1; off >>= 1) {
        p1 += __shfl_xor(p1, off);
        p2 += __shfl_xor(p2, off);
    }
    if (l == 0) lam[0] = expf(p1) - expf(p2) + LAMBDA_INIT;
}

// ---------- QKV GEMM: C = A(M,K) * Bt(N,K)^T, bf16 in, bf16 out ----------
// Q,K written per-head [NH][SEQ][128]; V written [SEQ][EMB].
__global__ __launch_bounds__(256) void k_gemm_qkv(const short* __restrict__ A,
                                                  const short* __restrict__ wqt,
                                                  const short* __restrict__ wkt,
                                                  const short* __restrict__ wvt,
                                                  short* __restrict__ Qh, short* __restrict__ Kh,
                                                  short* __restrict__ Vb) {
    const int bn = blockIdx.x * 64;
    const int bm = blockIdx.y * 64;
    const int nsel = bn >> 10;
    const int nloc = bn & 1023;
    const short* Bt = nsel == 0 ? wqt : (nsel == 1 ? wkt : wvt);
    short* C = nsel == 0 ? Qh : (nsel == 1 ? Kh : Vb);
    const int tid = threadIdx.x;
    const int w = tid >> 6, l = tid & 63;
    const int lr = l & 15, lg = l >> 4;
    const int mw = bm + (w >> 1) * 32;
    const int nw = nloc + (w & 1) * 32;
    f32x4 zero4 = {0.f, 0.f, 0.f, 0.f};
    f32x4 acc[2][2];
#pragma unroll
    for (int mi = 0; mi < 2; mi++)
#pragma unroll
        for (int ni = 0; ni < 2; ni++) acc[mi][ni] = zero4;
    for (int k0 = 0; k0 < EMB; k0 += 32) {
        short8_t a[2], b[2];
#pragma unroll
        for (int mi = 0; mi < 2; mi++)
            a[mi] = *(const short8_t*)(A + (mw + mi * 16 + lr) * EMB + k0 + lg * 8);
#pragma unroll
        for (int ni = 0; ni < 2; ni++)
            b[ni] = *(const short8_t*)(Bt + (nw + ni * 16 + lr) * EMB + k0 + lg * 8);
#pragma unroll
        for (int mi = 0; mi < 2; mi++)
#pragma unroll
            for (int ni = 0; ni < 2; ni++)
                acc[mi][ni] = __builtin_amdgcn_mfma_f32_16x16x32_bf16(a[mi], b[ni], acc[mi][ni], 0, 0, 0);
    }
    if (nsel < 2) {
#pragma unroll
        for (int mi = 0; mi < 2; mi++)
#pragma unroll
            for (int ni = 0; ni < 2; ni++)
#pragma unroll
                for (int r = 0; r < 4; r++) {
                    int row = mw + mi * 16 + lg * 4 + r;
                    int col = nw + ni * 16 + lr;
                    int hh = col >> 7, c = col & 127;
                    C[(hh << 18) + row * 128 + c] = f2bf(acc[mi][ni][r]);
                }
    } else {
#pragma unroll
        for (int mi = 0; mi < 2; mi++)
#pragma unroll
            for (int ni = 0; ni < 2; ni++)
#pragma unroll
                for (int r = 0; r < 4; r++) {
                    int row = mw + mi * 16 + lg * 4 + r;
                    int col = nw + ni * 16 + lr;
                    C[row * EMB + col] = f2bf(acc[mi][ni][r]);
                }
    }
}

// ---------- RoPE on Qh,Kh in place (per-head [8][2048][64] u32 pairs) ----------
__global__ void k_rope(short* __restrict__ Qh, short* __restrict__ Kh,
                       const float* __restrict__ cosT, const float* __restrict__ sinT) {
    int i = blockIdx.x * blockDim.x + threadIdx.x;  // u32 pair index
    int s = (i >> 6) & 2047;
    int jf = i & 31;
    float c = cosT[s * 32 + jf], sn = sinT[s * 32 + jf];
    unsigned* qw = reinterpret_cast<unsigned*>(Qh);
    unsigned* kw = reinterpret_cast<unsigned*>(Kh);
    unsigned v = qw[i];
    float e = bf2f((short)(v & 0xffff)), o = bf2f((short)(v >> 16));
    float r1 = e * c - o * sn, r2 = e * sn + o * c;
    qw[i] = ((unsigned)(unsigned short)f2bf(r2) << 16) | (unsigned)(unsigned short)f2bf(r1);
    v = kw[i];
    e = bf2f((short)(v & 0xffff));
    o = bf2f((short)(v >> 16));
    r1 = e * c - o * sn;
    r2 = e * sn + o * c;
    kw[i] = ((unsigned)(unsigned short)f2bf(r2) << 16) | (unsigned)(unsigned short)f2bf(r1);
}

// ---------- V transpose: (S, EMB) -> (EMB, S) ----------
__global__ void k_transpose_v(const short* __restrict__ Vb, short* __restrict__ Vt) {
    __shared__ short t[64][65];
    int s0 = blockIdx.x * 64, f0 = blockIdx.y * 64;
    int tid = threadIdx.x, col = tid & 63, rb = tid >> 6;
#pragma unroll
    for (int i = 0; i < 16; i++) {
        int row = rb + i * 4;
        t[row][col] = Vb[(s0 + row) * EMB + f0 + col];
    }
    __syncthreads();
#pragma unroll
    for (int i = 0; i < 16; i++) {
        int fr = rb + i * 4;
        Vt[(f0 + fr) * SEQ + s0 + col] = t[col][fr];
    }
}

// ---------- softmax + PV for one component of one tile ----------
__device__ __forceinline__ void soft_pv(const f32x4* s, float& m, float& lsum, f32x4* o,
                                        const short8_t* vf, short* myP, unsigned* myP32,
                                        int k0, int q0, int lq, int lg, bool edge) {
    float sv[8];
#pragma unroll
    for (int t = 0; t < 2; t++)
#pragma unroll
        for (int r = 0; r < 4; r++) sv[t * 4 + r] = s[t][r] * 0.125f;
    if (edge) {
#pragma unroll
        for (int t = 0; t < 2; t++)
#pragma unroll
            for (int r = 0; r < 4; r++)
                if (k0 + t * 16 + lg * 4 + r > q0 + lq) sv[t * 4 + r] = -1e30f;
    }
    float t1 = sv[0];
#pragma unroll
    for (int i = 1; i < 8; i++) t1 = fmaxf(t1, sv[i]);
    t1 = fmaxf(t1, __shfl_xor(t1, 16));
    t1 = fmaxf(t1, __shfl_xor(t1, 32));
    if (!__all(t1 <= m + 8.f)) {
        float mn = fmaxf(m, t1);
        float al = __expf(m - mn);
        m = mn;
        lsum *= al;
        float ar[4];
#pragma unroll
        for (int r = 0; r < 4; r++) ar[r] = __shfl(al, lg * 4 + r);
#pragma unroll
        for (int dt = 0; dt < 8; dt++)
#pragma unroll
            for (int r = 0; r < 4; r++) o[dt][r] *= ar[r];
    }
    float p[8];
#pragma unroll
    for (int i = 0; i < 8; i++) {
        p[i] = __expf(sv[i] - m);
        lsum += p[i];
    }
#pragma unroll
    for (int t = 0; t < 2; t++) {
        unsigned u0 = ((unsigned)(unsigned short)f2bf(p[t * 4 + 1]) << 16) |
                      (unsigned)(unsigned short)f2bf(p[t * 4 + 0]);
        unsigned u1 = ((unsigned)(unsigned short)f2bf(p[t * 4 + 3]) << 16) |
                      (unsigned)(unsigned short)f2bf(p[t * 4 + 2]);
        int base = lq * 20 + t * 8 + lg * 2;
        myP32[base] = u0;
        myP32[base + 1] = u1;
    }
    short8_t pa = *(const short8_t*)(myP + lq * 40 + lg * 8);
#pragma unroll
    for (int dt = 0; dt < 8; dt++)
        o[dt] = __builtin_amdgcn_mfma_f32_16x16x32_bf16(pa, vf[dt], o[dt], 0, 0, 0);
}

// ---------- block combine + RMS + subln + store for one tile ----------
__device__ __forceinline__ void combine_store(float m1, float l1v, float m2, float l2v,
                                              const f32x4* o1, const f32x4* o2,
                                              float OC[4][16][132], float ML[4][4][16],
                                              int w, int l, int lq, int lg, int tid, float lam,
                                              const float* __restrict__ subln,
                                              short* __restrict__ Ab, int q0, int h) {
    f32x4 zero4 = {0.f, 0.f, 0.f, 0.f};
    float l1 = l1v;
    l1 += __shfl_xor(l1, 16);
    l1 += __shfl_xor(l1, 32);
    float l2 = l2v;
    l2 += __shfl_xor(l2, 16);
    l2 += __shfl_xor(l2, 32);
    __syncthreads();  // protect ML/OC reuse across calls
    if (l < 16) {
        ML[w][0][l] = m1;
        ML[w][1][l] = l1;
        ML[w][2][l] = m2;
        ML[w][3][l] = l2;
    }
    __syncthreads();
    {
        float ww[4];
#pragma unroll
        for (int r = 0; r < 4; r++) {
            int qr = lg * 4 + r;
            float mx = fmaxf(fmaxf(ML[0][0][qr], ML[1][0][qr]), fmaxf(ML[2][0][qr], ML[3][0][qr]));
            ww[r] = __expf(ML[w][0][qr] - mx);
        }
#pragma unroll
        for (int dt = 0; dt < 8; dt++)
#pragma unroll
            for (int r = 0; r < 4; r++) OC[w][lg * 4 + r][dt * 16 + lq] = o1[dt][r] * ww[r];
    }
    __syncthreads();
    const int eq = tid >> 4;
    const int edv = (tid & 15) * 8;
    float co1[8];
    {
        f32x4 a0 = zero4, a1 = zero4;
#pragma unroll
        for (int ww = 0; ww < 4; ww++) {
            a0 += *(const f32x4*)&OC[ww][eq][edv];
            a1 += *(const f32x4*)&OC[ww][eq][edv + 4];
        }
#pragma unroll
        for (int j = 0; j < 4; j++) {
            co1[j] = a0[j];
            co1[4 + j] = a1[j];
        }
    }
    __syncthreads();
    {
        float ww[4];
#pragma unroll
        for (int r = 0; r < 4; r++) {
            int qr = lg * 4 + r;
            float mx = fmaxf(fmaxf(ML[0][2][qr], ML[1][2][qr]), fmaxf(ML[2][2][qr], ML[3][2][qr]));
            ww[r] = __expf(ML[w][2][qr] - mx);
        }
#pragma unroll
        for (int dt = 0; dt < 8; dt++)
#pragma unroll
            for (int r = 0; r < 4; r++) OC[w][lg * 4 + r][dt * 16 + lq] = o2[dt][r] * ww[r];
    }
    __syncthreads();
    float co2[8];
    {
        f32x4 a0 = zero4, a1 = zero4;
#pragma unroll
        for (int ww = 0; ww < 4; ww++) {
            a0 += *(const f32x4*)&OC[ww][eq][edv];
            a1 += *(const f32x4*)&OC[ww][eq][edv + 4];
        }
#pragma unroll
        for (int j = 0; j < 4; j++) {
            co2[j] = a0[j];
            co2[4 + j] = a1[j];
        }
    }
    float M1 = fmaxf(fmaxf(ML[0][0][eq], ML[1][0][eq]), fmaxf(ML[2][0][eq], ML[3][0][eq]));
    float M2 = fmaxf(fmaxf(ML[0][2][eq], ML[1][2][eq]), fmaxf(ML[2][2][eq], ML[3][2][eq]));
    float L1 = 0.f, L2 = 0.f;
#pragma unroll
    for (int ww = 0; ww < 4; ww++) {
        L1 += __expf(ML[ww][0][eq] - M1) * ML[ww][1][eq];
        L2 += __expf(ML[ww][2][eq] - M2) * ML[ww][3][eq];
    }
    float inv1 = 1.f / L1, inv2 = lam / L2;
    float a[8], ss = 0.f;
#pragma unroll
    for (int j = 0; j < 8; j++) {
        a[j] = co1[j] * inv1 - co2[j] * inv2;
        ss += a[j] * a[j];
    }
    ss += __shfl_xor(ss, 1);
    ss += __shfl_xor(ss, 2);
    ss += __shfl_xor(ss, 4);
    ss += __shfl_xor(ss, 8);
    float sc = rsqrtf(ss * (1.0f / 128.0f) + RMS_EPS) * ONE_MINUS_LI;
    short8_t r8;
#pragma unroll
    for (int j = 0; j < 8; j++) r8[j] = f2bf(a[j] * sc * subln[edv + j]);
    *(short8_t*)(Ab + (q0 + eq) * EMB + h * DVH + edv) = r8;
}

// ---------- fused differential flash attention, paired q-tiles ----------
// Block handles q-tiles bx and 127-bx (uniform total work). 4 waves split the
// KV range; each iteration loads K/V fragments ONCE and feeds both tiles'
// independent softmax/PV chains (2x reuse + 2x ILP).
__global__ __launch_bounds__(256) void k_attn(const short* __restrict__ Qh,
                                              const short* __restrict__ Kh,
                                              const short* __restrict__ Vt,
                                              const float* __restrict__ lamp,
                                              const float* __restrict__ subln,
                                              short* __restrict__ Ab) {
    const int h = blockIdx.y;
    const int bx = blockIdx.x;
    const int q0a = bx * 16;
    const int q0b = (127 - bx) * 16;
    const int tid = threadIdx.x;
    const int w = tid >> 6, l = tid & 63;
    const int lq = l & 15, lg = l >> 4;
    const float lam = lamp[0];

    __shared__ __align__(16) float OC[4][16][132];
    __shared__ float ML[4][4][16];
    __shared__ __align__(16) short PL[4][2][16][40];

    const short* qbase = Qh + ((size_t)h << 18);
    const short* kbase = Kh + ((size_t)h << 18);

    short8_t qa[4], qb[4];
    {
        const short* qp = qbase + (q0a + lq) * 128 + lg * 8;
        qa[0] = *(const short8_t*)(qp);
        qa[1] = *(const short8_t*)(qp + 32);
        qa[2] = *(const short8_t*)(qp + 64);
        qa[3] = *(const short8_t*)(qp + 96);
        qp = qbase + (q0b + lq) * 128 + lg * 8;
        qb[0] = *(const short8_t*)(qp);
        qb[1] = *(const short8_t*)(qp + 32);
        qb[2] = *(const short8_t*)(qp + 64);
        qb[3] = *(const short8_t*)(qp + 96);
    }
    f32x4 zero4 = {0.f, 0.f, 0.f, 0.f};
    f32x4 o1a[8], o2a[8], o1b[8], o2b[8];
#pragma unroll
    for (int dt = 0; dt < 8; dt++) {
        o1a[dt] = zero4;
        o2a[dt] = zero4;
        o1b[dt] = zero4;
        o2b[dt] = zero4;
    }
    float m1a = -1e30f, m2a = -1e30f, l1a = 0.f, l2a = 0.f;
    float m1b = -1e30f, m2b = -1e30f, l1b = 0.f, l2b = 0.f;
    short* Pa = &PL[w][0][0][0];
    short* Pb = &PL[w][1][0][0];
    unsigned* Pa32 = reinterpret_cast<unsigned*>(Pa);
    unsigned* Pb32 = reinterpret_cast<unsigned*>(Pb);

    const int nba = ((q0a + 16) + 31) >> 5;
    const int nbb = ((q0b + 16) + 31) >> 5;

    for (int kb = w; kb < nbb; kb += 4) {
        const int k0 = kb * 32;
        const bool doA = kb < nba;
        // V fragments first (longest latency, consumed last)
        short8_t vf[8];
#pragma unroll
        for (int dt = 0; dt < 8; dt++)
            vf[dt] = *(const short8_t*)(Vt + (h * DVH + dt * 16 + lq) * SEQ + k0 + lg * 8);
        const short* kp = kbase + (k0 + lq) * 128 + lg * 8;
        short8_t k1[2][2], k2[2][2];
#pragma unroll
        for (int t = 0; t < 2; t++) {
            k1[t][0] = *(const short8_t*)(kp + t * 16 * 128);
            k1[t][1] = *(const short8_t*)(kp + t * 16 * 128 + 32);
            k2[t][0] = *(const short8_t*)(kp + t * 16 * 128 + 64);
            k2[t][1] = *(const short8_t*)(kp + t * 16 * 128 + 96);
        }
        f32x4 s1b[2], s1a[2], s2b[2], s2a[2];
#pragma unroll
        for (int t = 0; t < 2; t++) {
            s1b[t] = zero4;
            s1b[t] = __builtin_amdgcn_mfma_f32_16x16x32_bf16(k1[t][0], qb[0], s1b[t], 0, 0, 0);
            s1b[t] = __builtin_amdgcn_mfma_f32_16x16x32_bf16(k1[t][1], qb[1], s1b[t], 0, 0, 0);
            s2b[t] = zero4;
            s2b[t] = __builtin_amdgcn_mfma_f32_16x16x32_bf16(k2[t][0], qb[2], s2b[t], 0, 0, 0);
            s2b[t] = __builtin_amdgcn_mfma_f32_16x16x32_bf16(k2[t][1], qb[3], s2b[t], 0, 0, 0);
        }
        if (doA) {
#pragma unroll
            for (int t = 0; t < 2; t++) {
                s1a[t] = zero4;
                s1a[t] = __builtin_amdgcn_mfma_f32_16x16x32_bf16(k1[t][0], qa[0], s1a[t], 0, 0, 0);
                s1a[t] = __builtin_amdgcn_mfma_f32_16x16x32_bf16(k1[t][1], qa[1], s1a[t], 0, 0, 0);
                s2a[t] = zero4;
                s2a[t] = __builtin_amdgcn_mfma_f32_16x16x32_bf16(k2[t][0], qa[2], s2a[t], 0, 0, 0);
                s2a[t] = __builtin_amdgcn_mfma_f32_16x16x32_bf16(k2[t][1], qa[3], s2a[t], 0, 0, 0);
            }
        }
        const bool eb = (k0 + 31 > q0b);
        soft_pv(s1b, m1b, l1b, o1b, vf, Pb, Pb32, k0, q0b, lq, lg, eb);
        if (doA) {
            const bool ea = (k0 + 31 > q0a);
            soft_pv(s1a, m1a, l1a, o1a, vf, Pa, Pa32, k0, q0a, lq, lg, ea);
        }
        soft_pv(s2b, m2b, l2b, o2b, vf, Pb, Pb32, k0, q0b, lq, lg, eb);
        if (doA) {
            const bool ea = (k0 + 31 > q0a);
            soft_pv(s2a, m2a, l2a, o2a, vf, Pa, Pa32, k0, q0a, lq, lg, ea);
        }
    }
    combine_store(m1b, l1b, m2b, l2b, o1b, o2b, OC, ML, w, l, lq, lg, tid, lam, subln, Ab, q0b, h);
    combine_store(m1a, l1a, m2a, l2a, o1a, o2a, OC, ML, w, l, lq, lg, tid, lam, subln, Ab, q0a, h);
}

// ---------- output GEMM: out = Ab(M,K) * wot(N,K)^T, f32 out ----------
__global__ __launch_bounds__(256) void k_gemm_out(const short* __restrict__ A,
                                                  const short* __restrict__ Bt,
                                                  float* __restrict__ C) {
    const int bn = blockIdx.x * 64;
    const int bm = blockIdx.y * 64;
    const int tid = threadIdx.x;
    const int w = tid >> 6, l = tid & 63;
    const int lr = l & 15, lg = l >> 4;
    const int mw = bm + (w >> 1) * 32;
    const int nw = bn + (w & 1) * 32;
    f32x4 zero4 = {0.f, 0.f, 0.f, 0.f};
    f32x4 acc[2][2];
#pragma unroll
    for (int mi = 0; mi < 2; mi++)
#pragma unroll
        for (int ni = 0; ni < 2; ni++) acc[mi][ni] = zero4;
    for (int k0 = 0; k0 < EMB; k0 += 32) {
        short8_t a[2], b[2];
#pragma unroll
        for (int mi = 0; mi < 2; mi++)
            a[mi] = *(const short8_t*)(A + (mw + mi * 16 + lr) * EMB + k0 + lg * 8);
#pragma unroll
        for (int ni = 0; ni < 2; ni++)
            b[ni] = *(const short8_t*)(Bt + (nw + ni * 16 + lr) * EMB + k0 + lg * 8);
#pragma unroll
        for (int mi = 0; mi < 2; mi++)
#pragma unroll
            for (int ni = 0; ni < 2; ni++)
                acc[mi][ni] = __builtin_amdgcn_mfma_f32_16x16x32_bf16(a[mi], b[ni], acc[mi][ni], 0, 0, 0);
    }
#pragma unroll
    for (int mi = 0; mi < 2; mi++)
#pragma unroll
        for (int ni = 0; ni < 2; ni++)
#pragma unroll
            for (int r = 0; r < 4; r++) {
                int row = mw + mi * 16 + lg * 4 + r;
                int col = nw + ni * 16 + lr;
                C[row * EMB + col] = acc[mi][ni][r];
            }
}

extern "C" void kernel_launch(void* const* d_in, const int* in_sizes, int n_in,
                              void* d_out, int out_size, void* d_ws, size_t ws_size,
                              hipStream_t stream) {
    const float* x = (const float*)d_in[0];
    const float* cosT = (const float*)d_in[1];
    const float* sinT = (const float*)d_in[2];
    const float* wq = (const float*)d_in[3];
    const float* wk = (const float*)d_in[4];
    const float* wv = (const float*)d_in[5];
    const float* wo = (const float*)d_in[6];
    const float* lq1 = (const float*)d_in[7];
    const float* lk1 = (const float*)d_in[8];
    const float* lq2 = (const float*)d_in[9];
    const float* lk2 = (const float*)d_in[10];
    const float* subln = (const float*)d_in[11];
    float* out = (float*)d_out;
    char* ws = (char*)d_ws;
    const size_t MB = 1 << 20;
    short* xb = (short*)(ws);
    short* wqt = (short*)(ws + 4 * MB);
    short* wkt = (short*)(ws + 6 * MB);
    short* wvt = (short*)(ws + 8 * MB);
    short* wot = (short*)(ws + 10 * MB);
    short* Qh = (short*)(ws + 12 * MB);
    short* Kh = (short*)(ws + 16 * MB);
    short* Vb = (short*)(ws + 20 * MB);
    short* Vt = (short*)(ws + 24 * MB);
    short* Ab = (short*)(ws + 28 * MB);
    float* lam = (float*)(ws + 32 * MB);

    k_convert_x<<<2048, 256, 0, stream>>>(x, xb);
    k_transpose_w<<<dim3(16, 16, 4), 256, 0, stream>>>(wq, wk, wv, wo, wqt, wkt, wvt, wot);
    k_lambda<<<1, 64, 0, stream>>>(lq1, lk1, lq2, lk2, lam);
    k_gemm_qkv<<<dim3(48, 32), 256, 0, stream>>>(xb, wqt, wkt, wvt, Qh, Kh, Vb);
    k_rope<<<4096, 256, 0, stream>>>(Qh, Kh, cosT, sinT);
    k_transpose_v<<<dim3(32, 16), 256, 0, stream>>>(Vb, Vt);
    k_attn<<<dim3(64, 8), 256, 0, stream>>>(Qh, Kh, Vt, lam, subln, Ab);
    k_gemm_out<<<dim3(16, 32), 256, 0, stream>>>(Ab, wot, out);
}

// Round 4
// 135.671 us; speedup vs baseline: 2.5903x; 1.5588x over previous
//
#include <hip/hip_runtime.h>
#include <hip/hip_bf16.h>

#define SEQ 2048
#define EMB 1024
#define NH 8
#define HD 64
#define DVH 128
#define LAMBDA_INIT 0.7836057665316245f
#define ONE_MINUS_LI 0.2163942334683755f
#define RMS_EPS 1e-5f

typedef __attribute__((ext_vector_type(8))) short short8_t;
typedef __attribute__((ext_vector_type(4))) float f32x4;

__device__ __forceinline__ short f2bf(float f) {
    __hip_bfloat16 h = __float2bfloat16(f);
    return *reinterpret_cast<short*>(&h);
}
__device__ __forceinline__ float bf2f(short s) {
    unsigned u = ((unsigned)(unsigned short)s) << 16;
    return __uint_as_float(u);
}
__device__ __forceinline__ void gload16(const void* g, void* l) {
    __builtin_amdgcn_global_load_lds((const __attribute__((address_space(1))) unsigned int*)g,
                                     (__attribute__((address_space(3))) unsigned int*)l, 16, 0, 0);
}

// ---------- prep: x f32 -> bf16 ----------
__global__ void k_convert_x(const float* __restrict__ x, short* __restrict__ xb) {
    int i = blockIdx.x * blockDim.x + threadIdx.x;
    const float4* xv = (const float4*)x;
    float4 v = xv[i];
    short4 r = make_short4(f2bf(v.x), f2bf(v.y), f2bf(v.z), f2bf(v.w));
    *(short4*)(xb + i * 4) = r;
}

// ---------- prep: weights f32 (K,N) -> bf16 transposed (N,K) ----------
__global__ void k_transpose_w(const float* __restrict__ w0, const float* __restrict__ w1,
                              const float* __restrict__ w2, const float* __restrict__ w3,
                              short* __restrict__ o0, short* __restrict__ o1,
                              short* __restrict__ o2, short* __restrict__ o3) {
    const float* w = blockIdx.z == 0 ? w0 : blockIdx.z == 1 ? w1 : blockIdx.z == 2 ? w2 : w3;
    short* o = blockIdx.z == 0 ? o0 : blockIdx.z == 1 ? o1 : blockIdx.z == 2 ? o2 : o3;
    __shared__ float t[64][65];
    int r0 = blockIdx.y * 64, c0 = blockIdx.x * 64;
    int tid = threadIdx.x, col = tid & 63, rb = tid >> 6;
#pragma unroll
    for (int i = 0; i < 16; i++) {
        int row = rb + i * 4;
        t[row][col] = w[(r0 + row) * EMB + c0 + col];
    }
    __syncthreads();
#pragma unroll
    for (int i = 0; i < 16; i++) {
        int fr = rb + i * 4;
        o[(c0 + fr) * EMB + r0 + col] = f2bf(t[col][fr]);
    }
}

// ---------- prep: lambda scalar ----------
__global__ void k_lambda(const float* __restrict__ lq1, const float* __restrict__ lk1,
                         const float* __restrict__ lq2, const float* __restrict__ lk2,
                         float* __restrict__ lam) {
    int l = threadIdx.x;
    float p1 = lq1[l] * lk1[l], p2 = lq2[l] * lk2[l];
#pragma unroll
    for (int off = 32; off >= 1; off >>= 1) {
        p1 += __shfl_xor(p1, off);
        p2 += __shfl_xor(p2, off);
    }
    if (l == 0) lam[0] = expf(p1) - expf(p2) + LAMBDA_INIT;
}

// ---------- m97-style tiled GEMM: C = A(M,K) * Bt(N,K)^T ----------
// Block tile (MI*32)x(NI*32); 4 waves in 2x2, each wave MI*16 x NI*16.
// BK=64. LDS staged via global_load_lds w=16 with XOR chunk swizzle applied
// on the GLOBAL SOURCE (linear LDS dest, rule #21) and matched on ds_read.
// OUTM=0: QKV (bf16; Q/K per-head [8][2048][128], V flat [2048][1024])
// OUTM=1: f32 flat output.
template <int MI, int NI, int OUTM>
__global__ __launch_bounds__(256) void k_gemm(const short* __restrict__ A,
                                              const short* __restrict__ B0,
                                              const short* __restrict__ B1,
                                              const short* __restrict__ B2,
                                              short* __restrict__ Cq, short* __restrict__ Ck,
                                              short* __restrict__ Cv, float* __restrict__ Cf) {
    constexpr int BM = MI * 32, BN = NI * 32, BK = 64;
    __shared__ short Abuf[BM * BK];
    __shared__ short Bbuf[BN * BK];
    const int bn = blockIdx.x * BN;
    const int bm = blockIdx.y * BM;
    const int nsel = bn >> 10;
    const int nloc = bn & 1023;
    const short* Bt = nsel == 0 ? B0 : (nsel == 1 ? B1 : B2);
    const int tid = threadIdx.x;
    const int w = tid >> 6, l = tid & 63;
    const int lr = l & 15, lg = l >> 4;
    const int wm = (w >> 1) * (MI * 16), wn = (w & 1) * (NI * 16);
    const int lrow8 = l >> 3, lchunk = l & 7;
    const int schunk = (lchunk ^ lrow8) * 8;  // pre-swizzled source chunk (shorts)

    f32x4 acc[MI][NI];
#pragma unroll
    for (int mi = 0; mi < MI; mi++)
#pragma unroll
        for (int ni = 0; ni < NI; ni++) acc[mi][ni] = f32x4{0.f, 0.f, 0.f, 0.f};

    for (int k0 = 0; k0 < EMB; k0 += BK) {
        // stage A tile (BM x 64 shorts), 8 rows per instruction
#pragma unroll
        for (int j = 0; j < BM / 32; j++) {
            int r0 = w * (BM / 4) + j * 8;
            gload16(A + (size_t)(bm + r0 + lrow8) * EMB + k0 + schunk, &Abuf[r0 * BK]);
        }
#pragma unroll
        for (int j = 0; j < BN / 32; j++) {
            int r0 = w * (BN / 4) + j * 8;
            gload16(Bt + (size_t)(nloc + r0 + lrow8) * EMB + k0 + schunk, &Bbuf[r0 * BK]);
        }
        __syncthreads();
#pragma unroll
        for (int kk = 0; kk < 2; kk++) {
            const int pcs = (((kk << 2) + lg) ^ (lr & 7)) << 3;  // swizzled read chunk
            short8_t af[MI], bf[NI];
#pragma unroll
            for (int mi = 0; mi < MI; mi++)
                af[mi] = *(const short8_t*)&Abuf[(wm + mi * 16 + lr) * BK + pcs];
#pragma unroll
            for (int ni = 0; ni < NI; ni++)
                bf[ni] = *(const short8_t*)&Bbuf[(wn + ni * 16 + lr) * BK + pcs];
#pragma unroll
            for (int mi = 0; mi < MI; mi++)
#pragma unroll
                for (int ni = 0; ni < NI; ni++)
                    acc[mi][ni] =
                        __builtin_amdgcn_mfma_f32_16x16x32_bf16(af[mi], bf[ni], acc[mi][ni], 0, 0, 0);
        }
        __syncthreads();
    }
    // epilogue
#pragma unroll
    for (int mi = 0; mi < MI; mi++)
#pragma unroll
        for (int ni = 0; ni < NI; ni++)
#pragma unroll
            for (int r = 0; r < 4; r++) {
                int row = bm + wm + mi * 16 + lg * 4 + r;
                int col = wn + ni * 16 + lr;
                if (OUTM == 0) {
                    if (nsel < 2) {
                        int ci = nloc + col;
                        int hh = ci >> 7, c = ci & 127;
                        (nsel == 0 ? Cq : Ck)[(hh << 18) + row * 128 + c] = f2bf(acc[mi][ni][r]);
                    } else {
                        Cv[row * EMB + nloc + col] = f2bf(acc[mi][ni][r]);
                    }
                } else {
                    Cf[row * EMB + bn + col] = acc[mi][ni][r];
                }
            }
}

// ---------- RoPE on Qh,Kh in place (per-head [8][2048][64] u32 pairs) ----------
__global__ void k_rope(short* __restrict__ Qh, short* __restrict__ Kh,
                       const float* __restrict__ cosT, const float* __restrict__ sinT) {
    int i = blockIdx.x * blockDim.x + threadIdx.x;  // u32 pair index
    int s = (i >> 6) & 2047;
    int jf = i & 31;
    float c = cosT[s * 32 + jf], sn = sinT[s * 32 + jf];
    unsigned* qw = reinterpret_cast<unsigned*>(Qh);
    unsigned* kw = reinterpret_cast<unsigned*>(Kh);
    unsigned v = qw[i];
    float e = bf2f((short)(v & 0xffff)), o = bf2f((short)(v >> 16));
    float r1 = e * c - o * sn, r2 = e * sn + o * c;
    qw[i] = ((unsigned)(unsigned short)f2bf(r2) << 16) | (unsigned)(unsigned short)f2bf(r1);
    v = kw[i];
    e = bf2f((short)(v & 0xffff));
    o = bf2f((short)(v >> 16));
    r1 = e * c - o * sn;
    r2 = e * sn + o * c;
    kw[i] = ((unsigned)(unsigned short)f2bf(r2) << 16) | (unsigned)(unsigned short)f2bf(r1);
}

// ---------- V transpose: (S, EMB) -> (EMB, S) ----------
__global__ void k_transpose_v(const short* __restrict__ Vb, short* __restrict__ Vt) {
    __shared__ short t[64][65];
    int s0 = blockIdx.x * 64, f0 = blockIdx.y * 64;
    int tid = threadIdx.x, col = tid & 63, rb = tid >> 6;
#pragma unroll
    for (int i = 0; i < 16; i++) {
        int row = rb + i * 4;
        t[row][col] = Vb[(s0 + row) * EMB + f0 + col];
    }
    __syncthreads();
#pragma unroll
    for (int i = 0; i < 16; i++) {
        int fr = rb + i * 4;
        Vt[(f0 + fr) * SEQ + s0 + col] = t[col][fr];
    }
}

// ---------- softmax + PV for one component of one tile ----------
__device__ __forceinline__ void soft_pv(const f32x4* s, float& m, float& lsum, f32x4* o,
                                        const short8_t* vf, short* myP, unsigned* myP32,
                                        int k0, int q0, int lq, int lg, bool edge) {
    float sv[8];
#pragma unroll
    for (int t = 0; t < 2; t++)
#pragma unroll
        for (int r = 0; r < 4; r++) sv[t * 4 + r] = s[t][r] * 0.125f;
    if (edge) {
#pragma unroll
        for (int t = 0; t < 2; t++)
#pragma unroll
            for (int r = 0; r < 4; r++)
                if (k0 + t * 16 + lg * 4 + r > q0 + lq) sv[t * 4 + r] = -1e30f;
    }
    float t1 = sv[0];
#pragma unroll
    for (int i = 1; i < 8; i++) t1 = fmaxf(t1, sv[i]);
    t1 = fmaxf(t1, __shfl_xor(t1, 16));
    t1 = fmaxf(t1, __shfl_xor(t1, 32));
    if (!__all(t1 <= m + 8.f)) {
        float mn = fmaxf(m, t1);
        float al = __expf(m - mn);
        m = mn;
        lsum *= al;
        float ar[4];
#pragma unroll
        for (int r = 0; r < 4; r++) ar[r] = __shfl(al, lg * 4 + r);
#pragma unroll
        for (int dt = 0; dt < 8; dt++)
#pragma unroll
            for (int r = 0; r < 4; r++) o[dt][r] *= ar[r];
    }
    float p[8];
#pragma unroll
    for (int i = 0; i < 8; i++) {
        p[i] = __expf(sv[i] - m);
        lsum += p[i];
    }
#pragma unroll
    for (int t = 0; t < 2; t++) {
        unsigned u0 = ((unsigned)(unsigned short)f2bf(p[t * 4 + 1]) << 16) |
                      (unsigned)(unsigned short)f2bf(p[t * 4 + 0]);
        unsigned u1 = ((unsigned)(unsigned short)f2bf(p[t * 4 + 3]) << 16) |
                      (unsigned)(unsigned short)f2bf(p[t * 4 + 2]);
        int base = lq * 20 + t * 8 + lg * 2;
        myP32[base] = u0;
        myP32[base + 1] = u1;
    }
    short8_t pa = *(const short8_t*)(myP + lq * 40 + lg * 8);
#pragma unroll
    for (int dt = 0; dt < 8; dt++)
        o[dt] = __builtin_amdgcn_mfma_f32_16x16x32_bf16(pa, vf[dt], o[dt], 0, 0, 0);
}

// ---------- block combine + RMS + subln + store for one tile ----------
__device__ __forceinline__ void combine_store(float m1, float l1v, float m2, float l2v,
                                              const f32x4* o1, const f32x4* o2,
                                              float OC[4][16][132], float ML[4][4][16],
                                              int w, int l, int lq, int lg, int tid, float lam,
                                              const float* __restrict__ subln,
                                              short* __restrict__ Ab, int q0, int h) {
    f32x4 zero4 = {0.f, 0.f, 0.f, 0.f};
    float l1 = l1v;
    l1 += __shfl_xor(l1, 16);
    l1 += __shfl_xor(l1, 32);
    float l2 = l2v;
    l2 += __shfl_xor(l2, 16);
    l2 += __shfl_xor(l2, 32);
    __syncthreads();
    if (l < 16) {
        ML[w][0][l] = m1;
        ML[w][1][l] = l1;
        ML[w][2][l] = m2;
        ML[w][3][l] = l2;
    }
    __syncthreads();
    {
        float ww[4];
#pragma unroll
        for (int r = 0; r < 4; r++) {
            int qr = lg * 4 + r;
            float mx = fmaxf(fmaxf(ML[0][0][qr], ML[1][0][qr]), fmaxf(ML[2][0][qr], ML[3][0][qr]));
            ww[r] = __expf(ML[w][0][qr] - mx);
        }
#pragma unroll
        for (int dt = 0; dt < 8; dt++)
#pragma unroll
            for (int r = 0; r < 4; r++) OC[w][lg * 4 + r][dt * 16 + lq] = o1[dt][r] * ww[r];
    }
    __syncthreads();
    const int eq = tid >> 4;
    const int edv = (tid & 15) * 8;
    float co1[8];
    {
        f32x4 a0 = zero4, a1 = zero4;
#pragma unroll
        for (int ww = 0; ww < 4; ww++) {
            a0 += *(const f32x4*)&OC[ww][eq][edv];
            a1 += *(const f32x4*)&OC[ww][eq][edv + 4];
        }
#pragma unroll
        for (int j = 0; j < 4; j++) {
            co1[j] = a0[j];
            co1[4 + j] = a1[j];
        }
    }
    __syncthreads();
    {
        float ww[4];
#pragma unroll
        for (int r = 0; r < 4; r++) {
            int qr = lg * 4 + r;
            float mx = fmaxf(fmaxf(ML[0][2][qr], ML[1][2][qr]), fmaxf(ML[2][2][qr], ML[3][2][qr]));
            ww[r] = __expf(ML[w][2][qr] - mx);
        }
#pragma unroll
        for (int dt = 0; dt < 8; dt++)
#pragma unroll
            for (int r = 0; r < 4; r++) OC[w][lg * 4 + r][dt * 16 + lq] = o2[dt][r] * ww[r];
    }
    __syncthreads();
    float co2[8];
    {
        f32x4 a0 = zero4, a1 = zero4;
#pragma unroll
        for (int ww = 0; ww < 4; ww++) {
            a0 += *(const f32x4*)&OC[ww][eq][edv];
            a1 += *(const f32x4*)&OC[ww][eq][edv + 4];
        }
#pragma unroll
        for (int j = 0; j < 4; j++) {
            co2[j] = a0[j];
            co2[4 + j] = a1[j];
        }
    }
    float M1 = fmaxf(fmaxf(ML[0][0][eq], ML[1][0][eq]), fmaxf(ML[2][0][eq], ML[3][0][eq]));
    float M2 = fmaxf(fmaxf(ML[0][2][eq], ML[1][2][eq]), fmaxf(ML[2][2][eq], ML[3][2][eq]));
    float L1 = 0.f, L2 = 0.f;
#pragma unroll
    for (int ww = 0; ww < 4; ww++) {
        L1 += __expf(ML[ww][0][eq] - M1) * ML[ww][1][eq];
        L2 += __expf(ML[ww][2][eq] - M2) * ML[ww][3][eq];
    }
    float inv1 = 1.f / L1, inv2 = lam / L2;
    float a[8], ss = 0.f;
#pragma unroll
    for (int j = 0; j < 8; j++) {
        a[j] = co1[j] * inv1 - co2[j] * inv2;
        ss += a[j] * a[j];
    }
    ss += __shfl_xor(ss, 1);
    ss += __shfl_xor(ss, 2);
    ss += __shfl_xor(ss, 4);
    ss += __shfl_xor(ss, 8);
    float sc = rsqrtf(ss * (1.0f / 128.0f) + RMS_EPS) * ONE_MINUS_LI;
    short8_t r8;
#pragma unroll
    for (int j = 0; j < 8; j++) r8[j] = f2bf(a[j] * sc * subln[edv + j]);
    *(short8_t*)(Ab + (q0 + eq) * EMB + h * DVH + edv) = r8;
}

// ---------- fused differential flash attention, paired q-tiles ----------
__global__ __launch_bounds__(256) void k_attn(const short* __restrict__ Qh,
                                              const short* __restrict__ Kh,
                                              const short* __restrict__ Vt,
                                              const float* __restrict__ lamp,
                                              const float* __restrict__ subln,
                                              short* __restrict__ Ab) {
    const int h = blockIdx.y;
    const int bx = blockIdx.x;
    const int q0a = bx * 16;
    const int q0b = (127 - bx) * 16;
    const int tid = threadIdx.x;
    const int w = tid >> 6, l = tid & 63;
    const int lq = l & 15, lg = l >> 4;
    const float lam = lamp[0];

    __shared__ __align__(16) float OC[4][16][132];
    __shared__ float ML[4][4][16];
    __shared__ __align__(16) short PL[4][2][16][40];

    const short* qbase = Qh + ((size_t)h << 18);
    const short* kbase = Kh + ((size_t)h << 18);

    short8_t qa[4], qb[4];
    {
        const short* qp = qbase + (q0a + lq) * 128 + lg * 8;
        qa[0] = *(const short8_t*)(qp);
        qa[1] = *(const short8_t*)(qp + 32);
        qa[2] = *(const short8_t*)(qp + 64);
        qa[3] = *(const short8_t*)(qp + 96);
        qp = qbase + (q0b + lq) * 128 + lg * 8;
        qb[0] = *(const short8_t*)(qp);
        qb[1] = *(const short8_t*)(qp + 32);
        qb[2] = *(const short8_t*)(qp + 64);
        qb[3] = *(const short8_t*)(qp + 96);
    }
    f32x4 zero4 = {0.f, 0.f, 0.f, 0.f};
    f32x4 o1a[8], o2a[8], o1b[8], o2b[8];
#pragma unroll
    for (int dt = 0; dt < 8; dt++) {
        o1a[dt] = zero4;
        o2a[dt] = zero4;
        o1b[dt] = zero4;
        o2b[dt] = zero4;
    }
    float m1a = -1e30f, m2a = -1e30f, l1a = 0.f, l2a = 0.f;
    float m1b = -1e30f, m2b = -1e30f, l1b = 0.f, l2b = 0.f;
    short* Pa = &PL[w][0][0][0];
    short* Pb = &PL[w][1][0][0];
    unsigned* Pa32 = reinterpret_cast<unsigned*>(Pa);
    unsigned* Pb32 = reinterpret_cast<unsigned*>(Pb);

    const int nba = ((q0a + 16) + 31) >> 5;
    const int nbb = ((q0b + 16) + 31) >> 5;

    for (int kb = w; kb < nbb; kb += 4) {
        const int k0 = kb * 32;
        const bool doA = kb < nba;
        short8_t vf[8];
#pragma unroll
        for (int dt = 0; dt < 8; dt++)
            vf[dt] = *(const short8_t*)(Vt + (h * DVH + dt * 16 + lq) * SEQ + k0 + lg * 8);
        const short* kp = kbase + (k0 + lq) * 128 + lg * 8;
        short8_t k1[2][2], k2[2][2];
#pragma unroll
        for (int t = 0; t < 2; t++) {
            k1[t][0] = *(const short8_t*)(kp + t * 16 * 128);
            k1[t][1] = *(const short8_t*)(kp + t * 16 * 128 + 32);
            k2[t][0] = *(const short8_t*)(kp + t * 16 * 128 + 64);
            k2[t][1] = *(const short8_t*)(kp + t * 16 * 128 + 96);
        }
        f32x4 s1b[2], s1a[2], s2b[2], s2a[2];
#pragma unroll
        for (int t = 0; t < 2; t++) {
            s1b[t] = zero4;
            s1b[t] = __builtin_amdgcn_mfma_f32_16x16x32_bf16(k1[t][0], qb[0], s1b[t], 0, 0, 0);
            s1b[t] = __builtin_amdgcn_mfma_f32_16x16x32_bf16(k1[t][1], qb[1], s1b[t], 0, 0, 0);
            s2b[t] = zero4;
            s2b[t] = __builtin_amdgcn_mfma_f32_16x16x32_bf16(k2[t][0], qb[2], s2b[t], 0, 0, 0);
            s2b[t] = __builtin_amdgcn_mfma_f32_16x16x32_bf16(k2[t][1], qb[3], s2b[t], 0, 0, 0);
        }
        if (doA) {
#pragma unroll
            for (int t = 0; t < 2; t++) {
                s1a[t] = zero4;
                s1a[t] = __builtin_amdgcn_mfma_f32_16x16x32_bf16(k1[t][0], qa[0], s1a[t], 0, 0, 0);
                s1a[t] = __builtin_amdgcn_mfma_f32_16x16x32_bf16(k1[t][1], qa[1], s1a[t], 0, 0, 0);
                s2a[t] = zero4;
                s2a[t] = __builtin_amdgcn_mfma_f32_16x16x32_bf16(k2[t][0], qa[2], s2a[t], 0, 0, 0);
                s2a[t] = __builtin_amdgcn_mfma_f32_16x16x32_bf16(k2[t][1], qa[3], s2a[t], 0, 0, 0);
            }
        }
        const bool eb = (k0 + 31 > q0b);
        soft_pv(s1b, m1b, l1b, o1b, vf, Pb, Pb32, k0, q0b, lq, lg, eb);
        if (doA) {
            const bool ea = (k0 + 31 > q0a);
            soft_pv(s1a, m1a, l1a, o1a, vf, Pa, Pa32, k0, q0a, lq, lg, ea);
        }
        soft_pv(s2b, m2b, l2b, o2b, vf, Pb, Pb32, k0, q0b, lq, lg, eb);
        if (doA) {
            const bool ea = (k0 + 31 > q0a);
            soft_pv(s2a, m2a, l2a, o2a, vf, Pa, Pa32, k0, q0a, lq, lg, ea);
        }
    }
    combine_store(m1b, l1b, m2b, l2b, o1b, o2b, OC, ML, w, l, lq, lg, tid, lam, subln, Ab, q0b, h);
    combine_store(m1a, l1a, m2a, l2a, o1a, o2a, OC, ML, w, l, lq, lg, tid, lam, subln, Ab, q0a, h);
}

extern "C" void kernel_launch(void* const* d_in, const int* in_sizes, int n_in,
                              void* d_out, int out_size, void* d_ws, size_t ws_size,
                              hipStream_t stream) {
    const float* x = (const float*)d_in[0];
    const float* cosT = (const float*)d_in[1];
    const float* sinT = (const float*)d_in[2];
    const float* wq = (const float*)d_in[3];
    const float* wk = (const float*)d_in[4];
    const float* wv = (const float*)d_in[5];
    const float* wo = (const float*)d_in[6];
    const float* lq1 = (const float*)d_in[7];
    const float* lk1 = (const float*)d_in[8];
    const float* lq2 = (const float*)d_in[9];
    const float* lk2 = (const float*)d_in[10];
    const float* subln = (const float*)d_in[11];
    float* out = (float*)d_out;
    char* ws = (char*)d_ws;
    const size_t MB = 1 << 20;
    short* xb = (short*)(ws);
    short* wqt = (short*)(ws + 4 * MB);
    short* wkt = (short*)(ws + 6 * MB);
    short* wvt = (short*)(ws + 8 * MB);
    short* wot = (short*)(ws + 10 * MB);
    short* Qh = (short*)(ws + 12 * MB);
    short* Kh = (short*)(ws + 16 * MB);
    short* Vb = (short*)(ws + 20 * MB);
    short* Vt = (short*)(ws + 24 * MB);
    short* Ab = (short*)(ws + 28 * MB);
    float* lam = (float*)(ws + 32 * MB);

    k_convert_x<<<2048, 256, 0, stream>>>(x, xb);
    k_transpose_w<<<dim3(16, 16, 4), 256, 0, stream>>>(wq, wk, wv, wo, wqt, wkt, wvt, wot);
    k_lambda<<<1, 64, 0, stream>>>(lq1, lk1, lq2, lk2, lam);
    k_gemm<4, 4, 0><<<dim3(24, 16), 256, 0, stream>>>(xb, wqt, wkt, wvt, Qh, Kh, Vb, nullptr);
    k_rope<<<4096, 256, 0, stream>>>(Qh, Kh, cosT, sinT);
    k_transpose_v<<<dim3(32, 16), 256, 0, stream>>>(Vb, Vt);
    k_attn<<<dim3(64, 8), 256, 0, stream>>>(Qh, Kh, Vt, lam, subln, Ab);
    k_gemm<2, 4, 1><<<dim3(8, 32), 256, 0, stream>>>(Ab, wot, wot, wot, nullptr, nullptr, nullptr, out);
}